// Round 6
// baseline (220.466 us; speedup 1.0000x reference)
//
#include <hip/hip_runtime.h>
#include <hip/hip_bf16.h>

#define ALPHA 0.8f
#define SPB 64      // samples per block (encoder)
#define IVW 132     // fallback-path LDS row stride

typedef __attribute__((ext_vector_type(8))) short bf16x8;
typedef __attribute__((ext_vector_type(8))) unsigned short ushort8;
typedef __attribute__((ext_vector_type(4))) float f32x4;

__device__ __forceinline__ unsigned short bfu(float x) {
    __hip_bfloat16 h = __float2bfloat16(x);   // RNE
    return __builtin_bit_cast(unsigned short, h);
}
__device__ __forceinline__ float b2f(unsigned short u) {
    return __builtin_bit_cast(float, ((unsigned)u) << 16);
}

// ---------------- prep kernels (shared) ----------------
// collapse r1+r2 into G[144][32], c[32]  (verified R0-R2)
__global__ void prepA(const float* __restrict__ Wr1, float* __restrict__ M) {
    int idx = blockIdx.x * 256 + threadIdx.x;
    if (idx >= 144 * 128) return;
    int x = idx >> 7;
    int r = idx & 127;
    const float* row = Wr1 + (size_t)r * 1024;
    float s = 0.f;
    if (x < 64) {
        #pragma unroll
        for (int j = 0; j < 8; ++j) s += row[j * 128 + x];
    } else if (x < 128) {
        #pragma unroll
        for (int j = 0; j < 8; ++j) s += row[j * 128 + 64 + (x - 64)];
    } else if (x < 136) {
        int j = x - 128;
        for (int k = 0; k < 64; ++k) s += row[j * 128 + k];
    } else {
        int j = x - 136;
        for (int k = 0; k < 64; ++k) s += row[j * 128 + 64 + k];
    }
    M[x * 128 + r] = s;
}

__global__ void prepB(const float* __restrict__ M, const float* __restrict__ Wr2,
                      const float* __restrict__ br1, const float* __restrict__ br2,
                      float* __restrict__ G, float* __restrict__ c) {
    int idx = blockIdx.x * 256 + threadIdx.x;
    if (idx < 144 * 32) {
        int x = idx >> 5, o = idx & 31;
        const float* m = M + x * 128;
        const float* w = Wr2 + o * 128;
        float s = 0.f;
        for (int r = 0; r < 128; ++r) s = fmaf(m[r], w[r], s);
        G[x * 32 + o] = s;
    } else if (idx < 144 * 32 + 32) {
        int o = idx - 144 * 32;
        const float* w = Wr2 + o * 128;
        float s = br2[o];
        for (int r = 0; r < 128; ++r) s = fmaf(br1[r], w[r], s);
        c[o] = s;
    }
}

// ======================= SPLIT PATH =======================
// Packed W layout per encoder: 4 quarters x [64 rows][24 phys chunks][8 bf16],
// phys = (c&24) | ((c&7) ^ (r&7))  -> LDS stage is a linear 24 KB copy.
__global__ void prepWpk(const float* __restrict__ We1, const float* __restrict__ We2,
                        unsigned short* __restrict__ W1p, unsigned short* __restrict__ W2p) {
    int idx = blockIdx.x * 256 + threadIdx.x;
    if (idx >= 12288) return;
    int enc = idx / 6144;               // FIX R5: was idx & 6143 (6144 not pow2!)
    int ci = idx - enc * 6144;
    int kq = ci / 1536;
    int rem = ci % 1536;
    int r = rem / 24, cch = rem % 24;
    int phys = (cch & 24) | ((cch & 7) ^ (r & 7));
    ushort8 v;
    if (!enc) {
        int k0 = kq * 192 + cch * 8;
        #pragma unroll
        for (int e = 0; e < 8; ++e) v[e] = bfu(We1[r * 768 + k0 + e]);
        *(ushort8*)(W1p + kq * 12288 + r * 192 + phys * 8) = v;
    } else {
        int k0 = kq * 160 + cch * 8;
        #pragma unroll
        for (int e = 0; e < 8; ++e) {
            int k = k0 + e;
            v[e] = (cch < 20 && k < 600) ? bfu(We2[r * 600 + k]) : (unsigned short)0;
        }
        *(ushort8*)(W2p + kq * 12288 + r * 192 + phys * 8) = v;
    }
}

// Encoder: 256 thr = 4 waves; wave owns 16 samples x all 64 n.
// A-loads pipelined one quarter ahead; W tile staged as linear packed copy.
template <int NCH, int KQ, int KLEN>
__device__ __forceinline__ void encPk(const float* __restrict__ X,
                                      const unsigned short* __restrict__ Wpk,
                                      const float* __restrict__ bias,
                                      short* sW, unsigned short* __restrict__ ivb,
                                      int colbase, int s0, int t) {
    const int w = t >> 6, l = t & 63;
    const int r16 = l & 15, kg = l >> 4;
    const float* xrow = X + (size_t)(s0 + w * 16 + r16) * KLEN;

    f32x4 acc0 = {0.f,0.f,0.f,0.f}, acc1 = {0.f,0.f,0.f,0.f};
    f32x4 acc2 = {0.f,0.f,0.f,0.f}, acc3 = {0.f,0.f,0.f,0.f};
    f32x4 ra[2 * NCH];
    ushort8 wr[6];

    // prologue: quarter-0 A loads
    #pragma unroll
    for (int kk = 0; kk < NCH; ++kk) {
        const int kb = kk * 32 + kg * 8;
        if (KLEN % 32 == 0 || kb + 8 <= KLEN) {
            ra[2 * kk]     = *(const f32x4*)(xrow + kb);
            ra[2 * kk + 1] = *(const f32x4*)(xrow + kb + 4);
        } else {
            ra[2 * kk] = f32x4{0.f,0.f,0.f,0.f};
            ra[2 * kk + 1] = f32x4{0.f,0.f,0.f,0.f};
        }
    }

    #pragma unroll
    for (int kq = 0; kq < 4; ++kq) {
        __syncthreads();                       // prev tile reads complete
        // issue W stage loads (linear packed copy)
        const unsigned short* wsrc = Wpk + kq * 12288 + t * 8;
        #pragma unroll
        for (int j = 0; j < 6; ++j) wr[j] = *(const ushort8*)(wsrc + j * 2048);
        // convert current-quarter A raw -> bf16 frags (frees ra)
        bf16x8 frag[NCH];
        #pragma unroll
        for (int kk = 0; kk < NCH; ++kk) {
            ushort8 p;
            #pragma unroll
            for (int e = 0; e < 4; ++e) {
                p[e]     = bfu(ra[2 * kk][e]);
                p[4 + e] = bfu(ra[2 * kk + 1][e]);
            }
            frag[kk] = __builtin_bit_cast(bf16x8, p);
        }
        // issue next-quarter A loads (in flight across the barrier drain)
        if (kq < 3) {
            #pragma unroll
            for (int kk = 0; kk < NCH; ++kk) {
                const int kb = (kq + 1) * KQ + kk * 32 + kg * 8;
                if (KLEN % 32 == 0 || kb + 8 <= KLEN) {
                    ra[2 * kk]     = *(const f32x4*)(xrow + kb);
                    ra[2 * kk + 1] = *(const f32x4*)(xrow + kb + 4);
                } else {
                    ra[2 * kk] = f32x4{0.f,0.f,0.f,0.f};
                    ra[2 * kk + 1] = f32x4{0.f,0.f,0.f,0.f};
                }
            }
        }
        // write W tile
        #pragma unroll
        for (int j = 0; j < 6; ++j)
            *(ushort8*)((char*)sW + (j * 256 + t) * 16) = wr[j];
        __syncthreads();                       // tile ready
        // compute: NCH k-steps x 4 n-tiles
        #pragma unroll
        for (int kk = 0; kk < NCH; ++kk) {
            const int cch = kk * 4 + kg;
            const int c24 = cch & 24, c7 = cch & 7;
            const bf16x8 af = frag[kk];
            {
                const int n = r16;
                const bf16x8 bf = *(const bf16x8*)((const char*)sW + n * 384 + (c24 | (c7 ^ (n & 7))) * 16);
                acc0 = __builtin_amdgcn_mfma_f32_16x16x32_bf16(af, bf, acc0, 0, 0, 0);
            }
            {
                const int n = 16 + r16;
                const bf16x8 bf = *(const bf16x8*)((const char*)sW + n * 384 + (c24 | (c7 ^ (n & 7))) * 16);
                acc1 = __builtin_amdgcn_mfma_f32_16x16x32_bf16(af, bf, acc1, 0, 0, 0);
            }
            {
                const int n = 32 + r16;
                const bf16x8 bf = *(const bf16x8*)((const char*)sW + n * 384 + (c24 | (c7 ^ (n & 7))) * 16);
                acc2 = __builtin_amdgcn_mfma_f32_16x16x32_bf16(af, bf, acc2, 0, 0, 0);
            }
            {
                const int n = 48 + r16;
                const bf16x8 bf = *(const bf16x8*)((const char*)sW + n * 384 + (c24 | (c7 ^ (n & 7))) * 16);
                acc3 = __builtin_amdgcn_mfma_f32_16x16x32_bf16(af, bf, acc3, 0, 0, 0);
            }
        }
    }
    // C/D: col = lane&15 (=n offset), row = 4*(lane>>4)+reg (=sample offset)
    const float bz0 = bias[r16], bz1 = bias[16 + r16], bz2 = bias[32 + r16], bz3 = bias[48 + r16];
    const int rr = 4 * kg;
    #pragma unroll
    for (int reg = 0; reg < 4; ++reg) {
        const size_t base = (size_t)(s0 + w * 16 + rr + reg) * 128 + colbase;
        ivb[base +  0 + r16] = bfu(acc0[reg] + bz0);
        ivb[base + 16 + r16] = bfu(acc1[reg] + bz1);
        ivb[base + 32 + r16] = bfu(acc2[reg] + bz2);
        ivb[base + 48 + r16] = bfu(acc3[reg] + bz3);
    }
}

__global__ __launch_bounds__(256, 4)
void mica_enc(const float* __restrict__ f1, const float* __restrict__ f2,
              const unsigned short* __restrict__ W1p, const unsigned short* __restrict__ W2p,
              const float* __restrict__ be1, const float* __restrict__ be2,
              unsigned short* __restrict__ ivb) {
    __shared__ __align__(16) short sW[12288];   // 24 KB W tile
    const int t = threadIdx.x;
    const int s0 = blockIdx.x * SPB;
    encPk<6, 192, 768>(f1, W1p, be1, sW, ivb, 0,  s0, t);
    encPk<5, 160, 600>(f2, W2p, be2, sW, ivb, 64, s0, t);
}

// Tail: 4 threads per sample (q = lane&3), no LDS, width-4 shuffle reduces.
__global__ __launch_bounds__(256, 4)
void mica_tail(const unsigned short* __restrict__ ivb,
               const float* __restrict__ Waffa, const float* __restrict__ Waffv,
               const float* __restrict__ Wa, const float* __restrict__ Wv,
               const float* __restrict__ Wca, const float* __restrict__ Wcv,
               const float* __restrict__ Wha, const float* __restrict__ Whv,
               const float* __restrict__ G, const float* __restrict__ cvec,
               float* __restrict__ out) {
    const int gid = blockIdx.x * 256 + threadIdx.x;
    const int s = gid >> 2, q = gid & 3;
    const unsigned short* ivp = ivb + (size_t)s * 128;

    ushort8 ivr[16];
    #pragma unroll
    for (int i = 0; i < 16; ++i) ivr[i] = *(const ushort8*)(ivp + i * 8);

    // moments (full, per thread — no reduce needed)
    float sii = 0.f, siv = 0.f, svv = 0.f;
    #pragma unroll
    for (int i = 0; i < 8; ++i) {
        #pragma unroll
        for (int e = 0; e < 8; ++e) {
            const float a = b2f(ivr[i][e]), b = b2f(ivr[8 + i][e]);
            sii = fmaf(a, a, sii); siv = fmaf(a, b, siv); svv = fmaf(b, b, svv);
        }
    }

    // gates
    float ia[8], va[8];
    #pragma unroll
    for (int j = 0; j < 8; ++j) {
        ia[j] = tanhf((sii * Waffa[j * 2 + 0] + siv * Waffa[j * 2 + 1]) * 0.125f);
        va[j] = tanhf((siv * Waffv[j * 2 + 0] + svv * Waffv[j * 2 + 1]) * 0.125f);
    }

    // H_a, H_v for m = q*8 .. q*8+7
    float Ha[8], Hv[8];
    #pragma unroll
    for (int mi = 0; mi < 8; ++mi) {
        const int m = q * 8 + mi;
        float sa = 0.f, sv = 0.f;
        #pragma unroll
        for (int j = 0; j < 8; ++j) {
            sa = fmaf(ia[j], Wca[m * 8 + j], sa);
            sv = fmaf(va[j], Wcv[m * 8 + j], sv);
        }
        Ha[mi] = sa; Hv[mi] = sv;
    }
    #pragma unroll
    for (int i = 0; i < 8; ++i) {
        float fa[8], fb[8];
        #pragma unroll
        for (int e = 0; e < 8; ++e) { fa[e] = b2f(ivr[i][e]); fb[e] = b2f(ivr[8 + i][e]); }
        #pragma unroll
        for (int mi = 0; mi < 8; ++mi) {
            const int m = q * 8 + mi;
            const f32x4 wa0 = *(const f32x4*)(Wa + m * 64 + i * 8);
            const f32x4 wa1 = *(const f32x4*)(Wa + m * 64 + i * 8 + 4);
            const f32x4 wv0 = *(const f32x4*)(Wv + m * 64 + i * 8);
            const f32x4 wv1 = *(const f32x4*)(Wv + m * 64 + i * 8 + 4);
            #pragma unroll
            for (int e = 0; e < 4; ++e) {
                Ha[mi] = fmaf(fa[e], wa0[e], Ha[mi]);
                Ha[mi] = fmaf(fa[4 + e], wa1[e], Ha[mi]);
                Hv[mi] = fmaf(fb[e], wv0[e], Hv[mi]);
                Hv[mi] = fmaf(fb[4 + e], wv1[e], Hv[mi]);
            }
        }
    }
    #pragma unroll
    for (int mi = 0; mi < 8; ++mi) {
        Ha[mi] = fmaxf(ALPHA * Ha[mi], 0.f);
        Hv[mi] = fmaxf((1.f - ALPHA) * Hv[mi], 0.f);
    }

    // ha/hv: partial over this thread's m, reduce across the 4 q-lanes
    float ha[8], hv[8];
    #pragma unroll
    for (int j = 0; j < 8; ++j) {
        float hap = 0.f, hvp = 0.f;
        #pragma unroll
        for (int mi = 0; mi < 8; ++mi) {
            hap = fmaf(Ha[mi], Wha[j * 32 + q * 8 + mi], hap);
            hvp = fmaf(Hv[mi], Whv[j * 32 + q * 8 + mi], hvp);
        }
        hap += __shfl_xor(hap, 1, 4); hap += __shfl_xor(hap, 2, 4);
        hvp += __shfl_xor(hvp, 1, 4); hvp += __shfl_xor(hvp, 2, 4);
        ha[j] = hap; hv[j] = hvp;
    }

    // out = X[144] * G + c  for o = q*8 .. q*8+7
    float o8[8];
    #pragma unroll
    for (int oi = 0; oi < 8; ++oi) o8[oi] = cvec[q * 8 + oi];
    #pragma unroll
    for (int i = 0; i < 16; ++i) {
        float fx[8];
        #pragma unroll
        for (int e = 0; e < 8; ++e) fx[e] = b2f(ivr[i][e]);
        #pragma unroll
        for (int e = 0; e < 8; ++e) {
            const int k = i * 8 + e;
            const f32x4 g0 = *(const f32x4*)(G + k * 32 + q * 8);
            const f32x4 g1 = *(const f32x4*)(G + k * 32 + q * 8 + 4);
            #pragma unroll
            for (int oi = 0; oi < 4; ++oi) {
                o8[oi]     = fmaf(fx[e], g0[oi], o8[oi]);
                o8[4 + oi] = fmaf(fx[e], g1[oi], o8[4 + oi]);
            }
        }
    }
    #pragma unroll
    for (int j = 0; j < 8; ++j) {
        const float aj = ALPHA * ha[j];
        const float vj = (1.f - ALPHA) * hv[j];
        const f32x4 ga0 = *(const f32x4*)(G + (128 + j) * 32 + q * 8);
        const f32x4 ga1 = *(const f32x4*)(G + (128 + j) * 32 + q * 8 + 4);
        const f32x4 gv0 = *(const f32x4*)(G + (136 + j) * 32 + q * 8);
        const f32x4 gv1 = *(const f32x4*)(G + (136 + j) * 32 + q * 8 + 4);
        #pragma unroll
        for (int oi = 0; oi < 4; ++oi) {
            o8[oi]     = fmaf(aj, ga0[oi], o8[oi]);
            o8[4 + oi] = fmaf(aj, ga1[oi], o8[4 + oi]);
            o8[oi]     = fmaf(vj, gv0[oi], o8[oi]);
            o8[4 + oi] = fmaf(vj, gv1[oi], o8[4 + oi]);
        }
    }
    f32x4 v0 = {o8[0], o8[1], o8[2], o8[3]};
    f32x4 v1 = {o8[4], o8[5], o8[6], o8[7]};
    float* op = out + (size_t)s * 32 + q * 8;
    *(f32x4*)op = v0;
    *((f32x4*)op + 1) = v1;
}

// ======================= FALLBACK PATH (R2, verified) =======================
__global__ void prepW(const float* __restrict__ We1, const float* __restrict__ We2,
                      unsigned short* __restrict__ Wb1, unsigned short* __restrict__ Wb2) {
    int i = blockIdx.x * 256 + threadIdx.x;
    if (i < 64 * 768) Wb1[i] = bfu(We1[i]);
    if (i < 64 * 640) {
        int r = i / 640, k = i - r * 640;
        Wb2[i] = (k < 600) ? bfu(We2[r * 600 + k]) : (unsigned short)0;
    }
}

template <int ROWLEN, int KPAD, int KQ, int NCH>
__device__ __forceinline__ void encMF(const float* __restrict__ X,
                                      const unsigned short* __restrict__ Wb,
                                      const float* __restrict__ bias,
                                      short* sW, float* sIV,
                                      int colbase, int s0, int t) {
    const int w = t >> 6, l = t & 63;
    const int r16 = l & 15, kg = l >> 4;
    const float* xrow = X + (size_t)(s0 + w * 16 + r16) * ROWLEN;
    const int srow = t >> 2;
    const int sc0 = (t & 3) * 6;
    f32x4 acc0 = {0.f,0.f,0.f,0.f}, acc1 = {0.f,0.f,0.f,0.f};
    f32x4 acc2 = {0.f,0.f,0.f,0.f}, acc3 = {0.f,0.f,0.f,0.f};
    #pragma unroll
    for (int kq = 0; kq < 4; ++kq) {
        __syncthreads();
        const unsigned short* wsrc = Wb + srow * KPAD + kq * KQ;
        #pragma unroll
        for (int j = 0; j < 6; ++j) {
            const int c = sc0 + j;
            const int phys = (c & 24) | ((c & 7) ^ (srow & 7));
            ushort8 v;
            if (KQ == 192 || c < (KQ / 8)) {
                v = *(const ushort8*)(wsrc + c * 8);
            } else {
                for (int e = 0; e < 8; ++e) v[e] = 0;
            }
            *(ushort8*)((char*)sW + srow * 384 + phys * 16) = v;
        }
        __syncthreads();
        #pragma unroll
        for (int kk = 0; kk < NCH; ++kk) {
            const int kb = kq * KQ + kk * 32 + kg * 8;
            ushort8 pa;
            #pragma unroll
            for (int e = 0; e < 8; ++e) pa[e] = 0;
            if (ROWLEN == KPAD || kb < ROWLEN) {
                const float4 u = *(const float4*)(xrow + kb);
                const float4 v2 = *(const float4*)(xrow + kb + 4);
                pa[0] = bfu(u.x); pa[1] = bfu(u.y); pa[2] = bfu(u.z); pa[3] = bfu(u.w);
                pa[4] = bfu(v2.x); pa[5] = bfu(v2.y); pa[6] = bfu(v2.z); pa[7] = bfu(v2.w);
            }
            const bf16x8 af = __builtin_bit_cast(bf16x8, pa);
            const int c = kk * 4 + kg;
            const int c24 = c & 24, c7 = c & 7;
            {
                const int n = r16;
                const bf16x8 bf = *(const bf16x8*)((const char*)sW + n * 384 + (c24 | (c7 ^ (n & 7))) * 16);
                acc0 = __builtin_amdgcn_mfma_f32_16x16x32_bf16(af, bf, acc0, 0, 0, 0);
            }
            {
                const int n = 16 + r16;
                const bf16x8 bf = *(const bf16x8*)((const char*)sW + n * 384 + (c24 | (c7 ^ (n & 7))) * 16);
                acc1 = __builtin_amdgcn_mfma_f32_16x16x32_bf16(af, bf, acc1, 0, 0, 0);
            }
            {
                const int n = 32 + r16;
                const bf16x8 bf = *(const bf16x8*)((const char*)sW + n * 384 + (c24 | (c7 ^ (n & 7))) * 16);
                acc2 = __builtin_amdgcn_mfma_f32_16x16x32_bf16(af, bf, acc2, 0, 0, 0);
            }
            {
                const int n = 48 + r16;
                const bf16x8 bf = *(const bf16x8*)((const char*)sW + n * 384 + (c24 | (c7 ^ (n & 7))) * 16);
                acc3 = __builtin_amdgcn_mfma_f32_16x16x32_bf16(af, bf, acc3, 0, 0, 0);
            }
        }
    }
    const int rr = 4 * kg;
    #pragma unroll
    for (int reg = 0; reg < 4; ++reg) {
        const int row = w * 16 + rr + reg;
        sIV[row * IVW + colbase +  0 + r16] = acc0[reg] + bias[ 0 + r16];
        sIV[row * IVW + colbase + 16 + r16] = acc1[reg] + bias[16 + r16];
        sIV[row * IVW + colbase + 32 + r16] = acc2[reg] + bias[32 + r16];
        sIV[row * IVW + colbase + 48 + r16] = acc3[reg] + bias[48 + r16];
    }
}

__global__ __launch_bounds__(256, 2)
void mica_main(const float* __restrict__ f1, const float* __restrict__ f2,
               const unsigned short* __restrict__ Wb1, const unsigned short* __restrict__ Wb2,
               const float* __restrict__ be1, const float* __restrict__ be2,
               const float* __restrict__ Waffa, const float* __restrict__ Waffv,
               const float* __restrict__ Wa, const float* __restrict__ Wv,
               const float* __restrict__ Wca, const float* __restrict__ Wcv,
               const float* __restrict__ Wha, const float* __restrict__ Whv,
               const float* __restrict__ G, const float* __restrict__ cvec,
               float* __restrict__ out) {
    __shared__ float sIV[SPB * IVW];
    __shared__ float scratch[6144];
    short* sW = (short*)scratch;
    const int t = threadIdx.x;
    const int s0 = blockIdx.x * SPB;
    encMF<768, 768, 192, 6>(f1, Wb1, be1, sW, sIV, 0, s0, t);
    encMF<600, 640, 160, 5>(f2, Wb2, be2, sW, sIV, 64, s0, t);
    __syncthreads();
    const int s = t & 63;
    const int q = t >> 6;
    const float* iv = sIV + s * IVW;
    float* red = scratch;
    float sii = 0.f, siv = 0.f, svv = 0.f;
    #pragma unroll
    for (int h = 0; h < 2; ++h) {
        const f32x4 a0 = *(const f32x4*)(iv + q * 16 + h * 8);
        const f32x4 a1 = *(const f32x4*)(iv + q * 16 + h * 8 + 4);
        const f32x4 b0 = *(const f32x4*)(iv + 64 + q * 16 + h * 8);
        const f32x4 b1 = *(const f32x4*)(iv + 64 + q * 16 + h * 8 + 4);
        #pragma unroll
        for (int j = 0; j < 4; ++j) {
            sii = fmaf(a0[j], a0[j], sii); siv = fmaf(a0[j], b0[j], siv); svv = fmaf(b0[j], b0[j], svv);
            sii = fmaf(a1[j], a1[j], sii); siv = fmaf(a1[j], b1[j], siv); svv = fmaf(b1[j], b1[j], svv);
        }
    }
    red[(q * 3 + 0) * 64 + s] = sii;
    red[(q * 3 + 1) * 64 + s] = siv;
    red[(q * 3 + 2) * 64 + s] = svv;
    __syncthreads();
    sii = 0.f; siv = 0.f; svv = 0.f;
    #pragma unroll
    for (int g = 0; g < 4; ++g) {
        sii += red[(g * 3 + 0) * 64 + s];
        siv += red[(g * 3 + 1) * 64 + s];
        svv += red[(g * 3 + 2) * 64 + s];
    }
    float ia[8], va[8];
    #pragma unroll
    for (int j = 0; j < 8; ++j) {
        ia[j] = tanhf((sii * Waffa[j * 2 + 0] + siv * Waffa[j * 2 + 1]) * 0.125f);
        va[j] = tanhf((siv * Waffv[j * 2 + 0] + svv * Waffv[j * 2 + 1]) * 0.125f);
    }
    float Ha[8], Hv[8];
    #pragma unroll
    for (int mi = 0; mi < 8; ++mi) {
        const int m = q * 8 + mi;
        float sa = 0.f, sv = 0.f;
        #pragma unroll
        for (int j = 0; j < 8; ++j) {
            sa = fmaf(ia[j], Wca[m * 8 + j], sa);
            sv = fmaf(va[j], Wcv[m * 8 + j], sv);
        }
        Ha[mi] = sa; Hv[mi] = sv;
    }
    for (int k4 = 0; k4 < 64; k4 += 4) {
        const f32x4 a4 = *(const f32x4*)(iv + k4);
        const f32x4 b4 = *(const f32x4*)(iv + 64 + k4);
        #pragma unroll
        for (int mi = 0; mi < 8; ++mi) {
            const int m = q * 8 + mi;
            const f32x4 wa = *(const f32x4*)(Wa + m * 64 + k4);
            const f32x4 wv = *(const f32x4*)(Wv + m * 64 + k4);
            #pragma unroll
            for (int j = 0; j < 4; ++j) {
                Ha[mi] = fmaf(a4[j], wa[j], Ha[mi]);
                Hv[mi] = fmaf(b4[j], wv[j], Hv[mi]);
            }
        }
    }
    #pragma unroll
    for (int mi = 0; mi < 8; ++mi) {
        Ha[mi] = fmaxf(ALPHA * Ha[mi], 0.f);
        Hv[mi] = fmaxf((1.f - ALPHA) * Hv[mi], 0.f);
    }
    __syncthreads();
    #pragma unroll
    for (int j = 0; j < 8; ++j) {
        float hap = 0.f, hvp = 0.f;
        #pragma unroll
        for (int mi = 0; mi < 8; ++mi) {
            hap = fmaf(Ha[mi], Wha[j * 32 + q * 8 + mi], hap);
            hvp = fmaf(Hv[mi], Whv[j * 32 + q * 8 + mi], hvp);
        }
        red[(q * 16 + j) * 64 + s] = hap;
        red[(q * 16 + 8 + j) * 64 + s] = hvp;
    }
    __syncthreads();
    float ha[8], hv[8];
    #pragma unroll
    for (int j = 0; j < 8; ++j) {
        float sa = 0.f, sv = 0.f;
        #pragma unroll
        for (int g = 0; g < 4; ++g) {
            sa += red[(g * 16 + j) * 64 + s];
            sv += red[(g * 16 + 8 + j) * 64 + s];
        }
        ha[j] = sa; hv[j] = sv;
    }
    float o8[8];
    #pragma unroll
    for (int oi = 0; oi < 8; ++oi) o8[oi] = cvec[q * 8 + oi];
    for (int k4 = 0; k4 < 128; k4 += 4) {
        const f32x4 a4 = *(const f32x4*)(iv + k4);
        #pragma unroll
        for (int kk = 0; kk < 4; ++kk) {
            const f32x4 g0 = *(const f32x4*)(G + (k4 + kk) * 32 + q * 8);
            const f32x4 g1 = *(const f32x4*)(G + (k4 + kk) * 32 + q * 8 + 4);
            #pragma unroll
            for (int oi = 0; oi < 4; ++oi) {
                o8[oi]     = fmaf(a4[kk], g0[oi], o8[oi]);
                o8[4 + oi] = fmaf(a4[kk], g1[oi], o8[4 + oi]);
            }
        }
    }
    #pragma unroll
    for (int j = 0; j < 8; ++j) {
        const float aj = ALPHA * ha[j];
        const float vj = (1.f - ALPHA) * hv[j];
        const f32x4 ga0 = *(const f32x4*)(G + (128 + j) * 32 + q * 8);
        const f32x4 ga1 = *(const f32x4*)(G + (128 + j) * 32 + q * 8 + 4);
        const f32x4 gv0 = *(const f32x4*)(G + (136 + j) * 32 + q * 8);
        const f32x4 gv1 = *(const f32x4*)(G + (136 + j) * 32 + q * 8 + 4);
        #pragma unroll
        for (int oi = 0; oi < 4; ++oi) {
            o8[oi]     = fmaf(aj, ga0[oi], o8[oi]);
            o8[4 + oi] = fmaf(aj, ga1[oi], o8[4 + oi]);
            o8[oi]     = fmaf(vj, gv0[oi], o8[oi]);
            o8[4 + oi] = fmaf(vj, gv1[oi], o8[4 + oi]);
        }
    }
    f32x4 v0 = {o8[0], o8[1], o8[2], o8[3]};
    f32x4 v1 = {o8[4], o8[5], o8[6], o8[7]};
    float* op = out + (size_t)(s0 + s) * 32 + q * 8;
    *(f32x4*)op = v0;
    *((f32x4*)op + 1) = v1;
}

extern "C" void kernel_launch(void* const* d_in, const int* in_sizes, int n_in,
                              void* d_out, int out_size, void* d_ws, size_t ws_size,
                              hipStream_t stream) {
    const float* f1    = (const float*)d_in[0];
    const float* f2    = (const float*)d_in[1];
    const float* We1   = (const float*)d_in[2];
    const float* be1   = (const float*)d_in[3];
    const float* We2   = (const float*)d_in[4];
    const float* be2   = (const float*)d_in[5];
    const float* Waffa = (const float*)d_in[6];
    const float* Waffv = (const float*)d_in[7];
    const float* Wa    = (const float*)d_in[8];
    const float* Wv    = (const float*)d_in[9];
    const float* Wca   = (const float*)d_in[10];
    const float* Wcv   = (const float*)d_in[11];
    const float* Wha   = (const float*)d_in[12];
    const float* Whv   = (const float*)d_in[13];
    const float* Wr1   = (const float*)d_in[14];
    const float* br1   = (const float*)d_in[15];
    const float* Wr2   = (const float*)d_in[16];
    const float* br2   = (const float*)d_in[17];
    float* outp = (float*)d_out;

    const int Btot = in_sizes[0] / 768;

    // common ws layout: M[0,73728) G[73728,92160) c[92160,92288)
    float* M = (float*)d_ws;
    float* G = (float*)((char*)d_ws + 73728);
    float* c = (float*)((char*)d_ws + 92160);

    prepA<<<(144 * 128 + 255) / 256, 256, 0, stream>>>(Wr1, M);
    prepB<<<(144 * 32 + 32 + 255) / 256, 256, 0, stream>>>(M, Wr2, br1, br2, G, c);

    // split path extra: W1p[92288,+98304) W2p[190592,+98304) ivb[288896, +B*256)
    const size_t need = 288896 + (size_t)Btot * 256;
    if (ws_size >= need) {
        unsigned short* W1p = (unsigned short*)((char*)d_ws + 92288);
        unsigned short* W2p = (unsigned short*)((char*)d_ws + 190592);
        unsigned short* ivb = (unsigned short*)((char*)d_ws + 288896);
        prepWpk<<<48, 256, 0, stream>>>(We1, We2, W1p, W2p);
        mica_enc<<<Btot / SPB, 256, 0, stream>>>(f1, f2, W1p, W2p, be1, be2, ivb);
        mica_tail<<<(Btot * 4) / 256, 256, 0, stream>>>(ivb, Waffa, Waffv, Wa, Wv,
                                                        Wca, Wcv, Wha, Whv, G, c, outp);
    } else {
        unsigned short* Wb1 = (unsigned short*)((char*)d_ws + 92288);
        unsigned short* Wb2 = (unsigned short*)((char*)d_ws + 190592);
        prepW<<<(64 * 768 + 255) / 256, 256, 0, stream>>>(We1, We2, Wb1, Wb2);
        mica_main<<<Btot / SPB, 256, 0, stream>>>(f1, f2, Wb1, Wb2, be1, be2,
                                                  Waffa, Waffv, Wa, Wv, Wca, Wcv, Wha, Whv,
                                                  G, c, outp);
    }
}

// Round 7
// 91.975 us; speedup vs baseline: 2.3970x; 2.3970x over previous
//
#include <hip/hip_runtime.h>
#include <hip/hip_bf16.h>

#define ALPHA 0.8f
#define SPB 64      // samples per block (encoder)
#define IVW 132     // tail LDS row stride

typedef __attribute__((ext_vector_type(8))) short bf16x8;
typedef __attribute__((ext_vector_type(8))) unsigned short ushort8;
typedef __attribute__((ext_vector_type(4))) float f32x4;

__device__ __forceinline__ unsigned short bfu(float x) {
    __hip_bfloat16 h = __float2bfloat16(x);   // RNE
    return __builtin_bit_cast(unsigned short, h);
}
__device__ __forceinline__ float b2f(unsigned short u) {
    return __builtin_bit_cast(float, ((unsigned)u) << 16);
}

// ---------------- prep kernels ----------------
// collapse r1+r2 into G[144][32], c[32]  (verified R0-R2)
__global__ void prepA(const float* __restrict__ Wr1, float* __restrict__ M) {
    int idx = blockIdx.x * 256 + threadIdx.x;
    if (idx >= 144 * 128) return;
    int x = idx >> 7;
    int r = idx & 127;
    const float* row = Wr1 + (size_t)r * 1024;
    float s = 0.f;
    if (x < 64) {
        #pragma unroll
        for (int j = 0; j < 8; ++j) s += row[j * 128 + x];
    } else if (x < 128) {
        #pragma unroll
        for (int j = 0; j < 8; ++j) s += row[j * 128 + 64 + (x - 64)];
    } else if (x < 136) {
        int j = x - 128;
        for (int k = 0; k < 64; ++k) s += row[j * 128 + k];
    } else {
        int j = x - 136;
        for (int k = 0; k < 64; ++k) s += row[j * 128 + 64 + k];
    }
    M[x * 128 + r] = s;
}

__global__ void prepB(const float* __restrict__ M, const float* __restrict__ Wr2,
                      const float* __restrict__ br1, const float* __restrict__ br2,
                      float* __restrict__ G, float* __restrict__ c) {
    int idx = blockIdx.x * 256 + threadIdx.x;
    if (idx < 144 * 32) {
        int x = idx >> 5, o = idx & 31;
        const float* m = M + x * 128;
        const float* w = Wr2 + o * 128;
        float s = 0.f;
        for (int r = 0; r < 128; ++r) s = fmaf(m[r], w[r], s);
        G[x * 32 + o] = s;
    } else if (idx < 144 * 32 + 32) {
        int o = idx - 144 * 32;
        const float* w = Wr2 + o * 128;
        float s = br2[o];
        for (int r = 0; r < 128; ++r) s = fmaf(br1[r], w[r], s);
        c[o] = s;
    }
}

// Packed W layout per encoder: 4 quarters x [64 rows][24 phys chunks][8 bf16],
// phys = (c&24) | ((c&7) ^ (r&7))  -> LDS stage is a linear 24 KB copy.
__global__ void prepWpk(const float* __restrict__ We1, const float* __restrict__ We2,
                        unsigned short* __restrict__ W1p, unsigned short* __restrict__ W2p) {
    int idx = blockIdx.x * 256 + threadIdx.x;
    if (idx >= 12288) return;
    int enc = idx / 6144;               // (R5 fix: 6144 not pow2)
    int ci = idx - enc * 6144;
    int kq = ci / 1536;
    int rem = ci % 1536;
    int r = rem / 24, cch = rem % 24;
    int phys = (cch & 24) | ((cch & 7) ^ (r & 7));
    ushort8 v;
    if (!enc) {
        int k0 = kq * 192 + cch * 8;
        #pragma unroll
        for (int e = 0; e < 8; ++e) v[e] = bfu(We1[r * 768 + k0 + e]);
        *(ushort8*)(W1p + kq * 12288 + r * 192 + phys * 8) = v;
    } else {
        int k0 = kq * 160 + cch * 8;
        #pragma unroll
        for (int e = 0; e < 8; ++e) {
            int k = k0 + e;
            v[e] = (cch < 20 && k < 600) ? bfu(We2[r * 600 + k]) : (unsigned short)0;
        }
        *(ushort8*)(W2p + kq * 12288 + r * 192 + phys * 8) = v;
    }
}

// ---------------- encoder (R6, measured at HBM floor ~30us) ----------------
template <int NCH, int KQ, int KLEN>
__device__ __forceinline__ void encPk(const float* __restrict__ X,
                                      const unsigned short* __restrict__ Wpk,
                                      const float* __restrict__ bias,
                                      short* sW, unsigned short* __restrict__ ivb,
                                      int colbase, int s0, int t) {
    const int w = t >> 6, l = t & 63;
    const int r16 = l & 15, kg = l >> 4;
    const float* xrow = X + (size_t)(s0 + w * 16 + r16) * KLEN;

    f32x4 acc0 = {0.f,0.f,0.f,0.f}, acc1 = {0.f,0.f,0.f,0.f};
    f32x4 acc2 = {0.f,0.f,0.f,0.f}, acc3 = {0.f,0.f,0.f,0.f};
    f32x4 ra[2 * NCH];
    ushort8 wr[6];

    // prologue: quarter-0 A loads
    #pragma unroll
    for (int kk = 0; kk < NCH; ++kk) {
        const int kb = kk * 32 + kg * 8;
        if (KLEN % 32 == 0 || kb + 8 <= KLEN) {
            ra[2 * kk]     = *(const f32x4*)(xrow + kb);
            ra[2 * kk + 1] = *(const f32x4*)(xrow + kb + 4);
        } else {
            ra[2 * kk] = f32x4{0.f,0.f,0.f,0.f};
            ra[2 * kk + 1] = f32x4{0.f,0.f,0.f,0.f};
        }
    }

    #pragma unroll
    for (int kq = 0; kq < 4; ++kq) {
        __syncthreads();                       // prev tile reads complete
        const unsigned short* wsrc = Wpk + kq * 12288 + t * 8;
        #pragma unroll
        for (int j = 0; j < 6; ++j) wr[j] = *(const ushort8*)(wsrc + j * 2048);
        // convert current-quarter A raw -> bf16 frags (frees ra)
        bf16x8 frag[NCH];
        #pragma unroll
        for (int kk = 0; kk < NCH; ++kk) {
            ushort8 p;
            #pragma unroll
            for (int e = 0; e < 4; ++e) {
                p[e]     = bfu(ra[2 * kk][e]);
                p[4 + e] = bfu(ra[2 * kk + 1][e]);
            }
            frag[kk] = __builtin_bit_cast(bf16x8, p);
        }
        // issue next-quarter A loads (in flight across the barrier drain)
        if (kq < 3) {
            #pragma unroll
            for (int kk = 0; kk < NCH; ++kk) {
                const int kb = (kq + 1) * KQ + kk * 32 + kg * 8;
                if (KLEN % 32 == 0 || kb + 8 <= KLEN) {
                    ra[2 * kk]     = *(const f32x4*)(xrow + kb);
                    ra[2 * kk + 1] = *(const f32x4*)(xrow + kb + 4);
                } else {
                    ra[2 * kk] = f32x4{0.f,0.f,0.f,0.f};
                    ra[2 * kk + 1] = f32x4{0.f,0.f,0.f,0.f};
                }
            }
        }
        // write W tile
        #pragma unroll
        for (int j = 0; j < 6; ++j)
            *(ushort8*)((char*)sW + (j * 256 + t) * 16) = wr[j];
        __syncthreads();                       // tile ready
        // compute: NCH k-steps x 4 n-tiles
        #pragma unroll
        for (int kk = 0; kk < NCH; ++kk) {
            const int cch = kk * 4 + kg;
            const int c24 = cch & 24, c7 = cch & 7;
            const bf16x8 af = frag[kk];
            {
                const int n = r16;
                const bf16x8 bf = *(const bf16x8*)((const char*)sW + n * 384 + (c24 | (c7 ^ (n & 7))) * 16);
                acc0 = __builtin_amdgcn_mfma_f32_16x16x32_bf16(af, bf, acc0, 0, 0, 0);
            }
            {
                const int n = 16 + r16;
                const bf16x8 bf = *(const bf16x8*)((const char*)sW + n * 384 + (c24 | (c7 ^ (n & 7))) * 16);
                acc1 = __builtin_amdgcn_mfma_f32_16x16x32_bf16(af, bf, acc1, 0, 0, 0);
            }
            {
                const int n = 32 + r16;
                const bf16x8 bf = *(const bf16x8*)((const char*)sW + n * 384 + (c24 | (c7 ^ (n & 7))) * 16);
                acc2 = __builtin_amdgcn_mfma_f32_16x16x32_bf16(af, bf, acc2, 0, 0, 0);
            }
            {
                const int n = 48 + r16;
                const bf16x8 bf = *(const bf16x8*)((const char*)sW + n * 384 + (c24 | (c7 ^ (n & 7))) * 16);
                acc3 = __builtin_amdgcn_mfma_f32_16x16x32_bf16(af, bf, acc3, 0, 0, 0);
            }
        }
    }
    // C/D: col = lane&15 (=n offset), row = 4*(lane>>4)+reg (=sample offset)
    const float bz0 = bias[r16], bz1 = bias[16 + r16], bz2 = bias[32 + r16], bz3 = bias[48 + r16];
    const int rr = 4 * kg;
    #pragma unroll
    for (int reg = 0; reg < 4; ++reg) {
        const size_t base = (size_t)(s0 + w * 16 + rr + reg) * 128 + colbase;
        ivb[base +  0 + r16] = bfu(acc0[reg] + bz0);
        ivb[base + 16 + r16] = bfu(acc1[reg] + bz1);
        ivb[base + 32 + r16] = bfu(acc2[reg] + bz2);
        ivb[base + 48 + r16] = bfu(acc3[reg] + bz3);
    }
}

__global__ __launch_bounds__(256, 4)
void mica_enc(const float* __restrict__ f1, const float* __restrict__ f2,
              const unsigned short* __restrict__ W1p, const unsigned short* __restrict__ W2p,
              const float* __restrict__ be1, const float* __restrict__ be2,
              unsigned short* __restrict__ ivb) {
    __shared__ __align__(16) short sW[12288];   // 24 KB W tile
    const int t = threadIdx.x;
    const int s0 = blockIdx.x * SPB;
    encPk<6, 192, 768>(f1, W1p, be1, sW, ivb, 0,  s0, t);
    encPk<5, 160, 600>(f2, W2p, be2, sW, ivb, 64, s0, t);
}

// ---------------- tail (R7: back to R2-verified LDS form; no spills) ----------------
// 256 threads / 64 samples per block. sIV staged from ivb; s = t&63, q = t>>6.
__global__ __launch_bounds__(256, 2)
void mica_tail(const unsigned short* __restrict__ ivb,
               const float* __restrict__ Waffa, const float* __restrict__ Waffv,
               const float* __restrict__ Wa, const float* __restrict__ Wv,
               const float* __restrict__ Wca, const float* __restrict__ Wcv,
               const float* __restrict__ Wha, const float* __restrict__ Whv,
               const float* __restrict__ G, const float* __restrict__ cvec,
               float* __restrict__ out) {
    __shared__ float sIV[SPB * IVW];    // 33.8 KB
    __shared__ float red[4096];         // 16 KB reduction buffer
    const int t = threadIdx.x;
    const int s0 = blockIdx.x * SPB;

    // stage: thread handles row = t&63, 32 cols at cb = (t>>6)*32
    {
        const int row = t & 63, cb = (t >> 6) * 32;
        const unsigned short* src = ivb + (size_t)(s0 + row) * 128 + cb;
        #pragma unroll
        for (int j = 0; j < 4; ++j) {
            const ushort8 v = *(const ushort8*)(src + j * 8);
            f32x4 f0 = {b2f(v[0]), b2f(v[1]), b2f(v[2]), b2f(v[3])};
            f32x4 f1 = {b2f(v[4]), b2f(v[5]), b2f(v[6]), b2f(v[7])};
            *(f32x4*)(sIV + row * IVW + cb + j * 8)     = f0;
            *(f32x4*)(sIV + row * IVW + cb + j * 8 + 4) = f1;
        }
    }
    __syncthreads();

    const int s = t & 63;
    const int q = t >> 6;
    const float* iv = sIV + s * IVW;

    // step 3: moments (4-way split over k, 16 k each)
    float sii = 0.f, siv = 0.f, svv = 0.f;
    #pragma unroll
    for (int h = 0; h < 2; ++h) {
        const f32x4 a0 = *(const f32x4*)(iv + q * 16 + h * 8);
        const f32x4 a1 = *(const f32x4*)(iv + q * 16 + h * 8 + 4);
        const f32x4 b0 = *(const f32x4*)(iv + 64 + q * 16 + h * 8);
        const f32x4 b1 = *(const f32x4*)(iv + 64 + q * 16 + h * 8 + 4);
        #pragma unroll
        for (int j = 0; j < 4; ++j) {
            sii = fmaf(a0[j], a0[j], sii); siv = fmaf(a0[j], b0[j], siv); svv = fmaf(b0[j], b0[j], svv);
            sii = fmaf(a1[j], a1[j], sii); siv = fmaf(a1[j], b1[j], siv); svv = fmaf(b1[j], b1[j], svv);
        }
    }
    red[(q * 3 + 0) * 64 + s] = sii;
    red[(q * 3 + 1) * 64 + s] = siv;
    red[(q * 3 + 2) * 64 + s] = svv;
    __syncthreads();
    sii = 0.f; siv = 0.f; svv = 0.f;
    #pragma unroll
    for (int g = 0; g < 4; ++g) {
        sii += red[(g * 3 + 0) * 64 + s];
        siv += red[(g * 3 + 1) * 64 + s];
        svv += red[(g * 3 + 2) * 64 + s];
    }

    // step 4: gates (scale = 1/8)
    float ia[8], va[8];
    #pragma unroll
    for (int j = 0; j < 8; ++j) {
        ia[j] = tanhf((sii * Waffa[j * 2 + 0] + siv * Waffa[j * 2 + 1]) * 0.125f);
        va[j] = tanhf((siv * Waffv[j * 2 + 0] + svv * Waffv[j * 2 + 1]) * 0.125f);
    }

    // steps 5-6: H_a, H_v — this thread owns m = q*8 .. q*8+7
    float Ha[8], Hv[8];
    #pragma unroll
    for (int mi = 0; mi < 8; ++mi) {
        const int m = q * 8 + mi;
        float sa = 0.f, sv = 0.f;
        #pragma unroll
        for (int j = 0; j < 8; ++j) {
            sa = fmaf(ia[j], Wca[m * 8 + j], sa);
            sv = fmaf(va[j], Wcv[m * 8 + j], sv);
        }
        Ha[mi] = sa; Hv[mi] = sv;
    }
    for (int k4 = 0; k4 < 64; k4 += 4) {
        const f32x4 a4 = *(const f32x4*)(iv + k4);
        const f32x4 b4 = *(const f32x4*)(iv + 64 + k4);
        #pragma unroll
        for (int mi = 0; mi < 8; ++mi) {
            const int m = q * 8 + mi;
            const f32x4 wa = *(const f32x4*)(Wa + m * 64 + k4);
            const f32x4 wv = *(const f32x4*)(Wv + m * 64 + k4);
            #pragma unroll
            for (int j = 0; j < 4; ++j) {
                Ha[mi] = fmaf(a4[j], wa[j], Ha[mi]);
                Hv[mi] = fmaf(b4[j], wv[j], Hv[mi]);
            }
        }
    }
    #pragma unroll
    for (int mi = 0; mi < 8; ++mi) {
        Ha[mi] = fmaxf(ALPHA * Ha[mi], 0.f);
        Hv[mi] = fmaxf((1.f - ALPHA) * Hv[mi], 0.f);
    }

    __syncthreads();   // step-3 reads of red done before step-7 writes

    // step 7: ha/hv partials (8 m each), reduce via red
    #pragma unroll
    for (int j = 0; j < 8; ++j) {
        float hap = 0.f, hvp = 0.f;
        #pragma unroll
        for (int mi = 0; mi < 8; ++mi) {
            hap = fmaf(Ha[mi], Wha[j * 32 + q * 8 + mi], hap);
            hvp = fmaf(Hv[mi], Whv[j * 32 + q * 8 + mi], hvp);
        }
        red[(q * 16 + j) * 64 + s] = hap;
        red[(q * 16 + 8 + j) * 64 + s] = hvp;
    }
    __syncthreads();
    float ha[8], hv[8];
    #pragma unroll
    for (int j = 0; j < 8; ++j) {
        float sa = 0.f, sv = 0.f;
        #pragma unroll
        for (int g = 0; g < 4; ++g) {
            sa += red[(g * 16 + j) * 64 + s];
            sv += red[(g * 16 + 8 + j) * 64 + s];
        }
        ha[j] = sa; hv[j] = sv;
    }

    // step 9: out = X[144] * G + c — this thread: o = q*8 .. q*8+7
    float o8[8];
    #pragma unroll
    for (int oi = 0; oi < 8; ++oi) o8[oi] = cvec[q * 8 + oi];
    for (int k4 = 0; k4 < 128; k4 += 4) {
        const f32x4 a4 = *(const f32x4*)(iv + k4);
        #pragma unroll
        for (int kk = 0; kk < 4; ++kk) {
            const f32x4 g0 = *(const f32x4*)(G + (k4 + kk) * 32 + q * 8);
            const f32x4 g1 = *(const f32x4*)(G + (k4 + kk) * 32 + q * 8 + 4);
            #pragma unroll
            for (int oi = 0; oi < 4; ++oi) {
                o8[oi]     = fmaf(a4[kk], g0[oi], o8[oi]);
                o8[4 + oi] = fmaf(a4[kk], g1[oi], o8[4 + oi]);
            }
        }
    }
    #pragma unroll
    for (int j = 0; j < 8; ++j) {
        const float aj = ALPHA * ha[j];
        const float vj = (1.f - ALPHA) * hv[j];
        const f32x4 ga0 = *(const f32x4*)(G + (128 + j) * 32 + q * 8);
        const f32x4 ga1 = *(const f32x4*)(G + (128 + j) * 32 + q * 8 + 4);
        const f32x4 gv0 = *(const f32x4*)(G + (136 + j) * 32 + q * 8);
        const f32x4 gv1 = *(const f32x4*)(G + (136 + j) * 32 + q * 8 + 4);
        #pragma unroll
        for (int oi = 0; oi < 4; ++oi) {
            o8[oi]     = fmaf(aj, ga0[oi], o8[oi]);
            o8[4 + oi] = fmaf(aj, ga1[oi], o8[4 + oi]);
            o8[oi]     = fmaf(vj, gv0[oi], o8[oi]);
            o8[4 + oi] = fmaf(vj, gv1[oi], o8[4 + oi]);
        }
    }
    f32x4 v0 = {o8[0], o8[1], o8[2], o8[3]};
    f32x4 v1 = {o8[4], o8[5], o8[6], o8[7]};
    float* op = out + (size_t)(s0 + s) * 32 + q * 8;
    *(f32x4*)op = v0;
    *((f32x4*)op + 1) = v1;
}

extern "C" void kernel_launch(void* const* d_in, const int* in_sizes, int n_in,
                              void* d_out, int out_size, void* d_ws, size_t ws_size,
                              hipStream_t stream) {
    const float* f1    = (const float*)d_in[0];
    const float* f2    = (const float*)d_in[1];
    const float* We1   = (const float*)d_in[2];
    const float* be1   = (const float*)d_in[3];
    const float* We2   = (const float*)d_in[4];
    const float* be2   = (const float*)d_in[5];
    const float* Waffa = (const float*)d_in[6];
    const float* Waffv = (const float*)d_in[7];
    const float* Wa    = (const float*)d_in[8];
    const float* Wv    = (const float*)d_in[9];
    const float* Wca   = (const float*)d_in[10];
    const float* Wcv   = (const float*)d_in[11];
    const float* Wha   = (const float*)d_in[12];
    const float* Whv   = (const float*)d_in[13];
    const float* Wr1   = (const float*)d_in[14];
    const float* br1   = (const float*)d_in[15];
    const float* Wr2   = (const float*)d_in[16];
    const float* br2   = (const float*)d_in[17];
    float* outp = (float*)d_out;

    const int Btot = in_sizes[0] / 768;

    // ws layout: M[0,73728) G[73728,92160) c[92160,92288)
    //            W1p[92288,+98304) W2p[190592,+98304) ivb[288896, +B*256)
    float* M = (float*)d_ws;
    float* G = (float*)((char*)d_ws + 73728);
    float* c = (float*)((char*)d_ws + 92160);
    unsigned short* W1p = (unsigned short*)((char*)d_ws + 92288);
    unsigned short* W2p = (unsigned short*)((char*)d_ws + 190592);
    unsigned short* ivb = (unsigned short*)((char*)d_ws + 288896);

    prepA<<<(144 * 128 + 255) / 256, 256, 0, stream>>>(Wr1, M);
    prepB<<<(144 * 32 + 32 + 255) / 256, 256, 0, stream>>>(M, Wr2, br1, br2, G, c);
    prepWpk<<<48, 256, 0, stream>>>(We1, We2, W1p, W2p);
    mica_enc<<<Btot / SPB, 256, 0, stream>>>(f1, f2, W1p, W2p, be1, be2, ivb);
    mica_tail<<<Btot / SPB, 256, 0, stream>>>(ivb, Waffa, Waffv, Wa, Wv,
                                              Wca, Wcv, Wha, Whv, G, c, outp);
}

// Round 8
// 91.627 us; speedup vs baseline: 2.4061x; 1.0038x over previous
//
#include <hip/hip_runtime.h>
#include <hip/hip_bf16.h>

#define ALPHA 0.8f
#define SPB 64      // samples per block (encoder)
#define IVW 132     // tail LDS row stride

typedef __attribute__((ext_vector_type(8))) short bf16x8;
typedef __attribute__((ext_vector_type(8))) unsigned short ushort8;
typedef __attribute__((ext_vector_type(4))) float f32x4;

__device__ __forceinline__ unsigned short bfu(float x) {
    __hip_bfloat16 h = __float2bfloat16(x);   // RNE
    return __builtin_bit_cast(unsigned short, h);
}
__device__ __forceinline__ float b2f(unsigned short u) {
    return __builtin_bit_cast(float, ((unsigned)u) << 16);
}

// ---------------- prep kernels ----------------
// collapse r1+r2 into G[144][32], c[32]  (verified R0-R2)
__global__ void prepA(const float* __restrict__ Wr1, float* __restrict__ M) {
    int idx = blockIdx.x * 256 + threadIdx.x;
    if (idx >= 144 * 128) return;
    int x = idx >> 7;
    int r = idx & 127;
    const float* row = Wr1 + (size_t)r * 1024;
    float s = 0.f;
    if (x < 64) {
        #pragma unroll
        for (int j = 0; j < 8; ++j) s += row[j * 128 + x];
    } else if (x < 128) {
        #pragma unroll
        for (int j = 0; j < 8; ++j) s += row[j * 128 + 64 + (x - 64)];
    } else if (x < 136) {
        int j = x - 128;
        for (int k = 0; k < 64; ++k) s += row[j * 128 + k];
    } else {
        int j = x - 136;
        for (int k = 0; k < 64; ++k) s += row[j * 128 + 64 + k];
    }
    M[x * 128 + r] = s;
}

__global__ void prepB(const float* __restrict__ M, const float* __restrict__ Wr2,
                      const float* __restrict__ br1, const float* __restrict__ br2,
                      float* __restrict__ G, float* __restrict__ c) {
    int idx = blockIdx.x * 256 + threadIdx.x;
    if (idx < 144 * 32) {
        int x = idx >> 5, o = idx & 31;
        const float* m = M + x * 128;
        const float* w = Wr2 + o * 128;
        float s = 0.f;
        for (int r = 0; r < 128; ++r) s = fmaf(m[r], w[r], s);
        G[x * 32 + o] = s;
    } else if (idx < 144 * 32 + 32) {
        int o = idx - 144 * 32;
        const float* w = Wr2 + o * 128;
        float s = br2[o];
        for (int r = 0; r < 128; ++r) s = fmaf(br1[r], w[r], s);
        c[o] = s;
    }
}

// Packed W layout per encoder: 4 quarters x [64 rows][24 phys chunks][8 bf16],
// phys = (c&24) | ((c&7) ^ (r&7))  -> LDS stage is a linear 24 KB copy.
__global__ void prepWpk(const float* __restrict__ We1, const float* __restrict__ We2,
                        unsigned short* __restrict__ W1p, unsigned short* __restrict__ W2p) {
    int idx = blockIdx.x * 256 + threadIdx.x;
    if (idx >= 12288) return;
    int enc = idx / 6144;               // (R5 fix: 6144 not pow2)
    int ci = idx - enc * 6144;
    int kq = ci / 1536;
    int rem = ci % 1536;
    int r = rem / 24, cch = rem % 24;
    int phys = (cch & 24) | ((cch & 7) ^ (r & 7));
    ushort8 v;
    if (!enc) {
        int k0 = kq * 192 + cch * 8;
        #pragma unroll
        for (int e = 0; e < 8; ++e) v[e] = bfu(We1[r * 768 + k0 + e]);
        *(ushort8*)(W1p + kq * 12288 + r * 192 + phys * 8) = v;
    } else {
        int k0 = kq * 160 + cch * 8;
        #pragma unroll
        for (int e = 0; e < 8; ++e) {
            int k = k0 + e;
            v[e] = (cch < 20 && k < 600) ? bfu(We2[r * 600 + k]) : (unsigned short)0;
        }
        *(ushort8*)(W2p + kq * 12288 + r * 192 + phys * 8) = v;
    }
}

// ---------------- encoder (R6, measured at HBM floor ~30us) ----------------
template <int NCH, int KQ, int KLEN>
__device__ __forceinline__ void encPk(const float* __restrict__ X,
                                      const unsigned short* __restrict__ Wpk,
                                      const float* __restrict__ bias,
                                      short* sW, unsigned short* __restrict__ ivb,
                                      int colbase, int s0, int t) {
    const int w = t >> 6, l = t & 63;
    const int r16 = l & 15, kg = l >> 4;
    const float* xrow = X + (size_t)(s0 + w * 16 + r16) * KLEN;

    f32x4 acc0 = {0.f,0.f,0.f,0.f}, acc1 = {0.f,0.f,0.f,0.f};
    f32x4 acc2 = {0.f,0.f,0.f,0.f}, acc3 = {0.f,0.f,0.f,0.f};
    f32x4 ra[2 * NCH];
    ushort8 wr[6];

    // prologue: quarter-0 A loads
    #pragma unroll
    for (int kk = 0; kk < NCH; ++kk) {
        const int kb = kk * 32 + kg * 8;
        if (KLEN % 32 == 0 || kb + 8 <= KLEN) {
            ra[2 * kk]     = *(const f32x4*)(xrow + kb);
            ra[2 * kk + 1] = *(const f32x4*)(xrow + kb + 4);
        } else {
            ra[2 * kk] = f32x4{0.f,0.f,0.f,0.f};
            ra[2 * kk + 1] = f32x4{0.f,0.f,0.f,0.f};
        }
    }

    #pragma unroll
    for (int kq = 0; kq < 4; ++kq) {
        __syncthreads();                       // prev tile reads complete
        const unsigned short* wsrc = Wpk + kq * 12288 + t * 8;
        #pragma unroll
        for (int j = 0; j < 6; ++j) wr[j] = *(const ushort8*)(wsrc + j * 2048);
        // convert current-quarter A raw -> bf16 frags (frees ra)
        bf16x8 frag[NCH];
        #pragma unroll
        for (int kk = 0; kk < NCH; ++kk) {
            ushort8 p;
            #pragma unroll
            for (int e = 0; e < 4; ++e) {
                p[e]     = bfu(ra[2 * kk][e]);
                p[4 + e] = bfu(ra[2 * kk + 1][e]);
            }
            frag[kk] = __builtin_bit_cast(bf16x8, p);
        }
        // issue next-quarter A loads (in flight across the barrier drain)
        if (kq < 3) {
            #pragma unroll
            for (int kk = 0; kk < NCH; ++kk) {
                const int kb = (kq + 1) * KQ + kk * 32 + kg * 8;
                if (KLEN % 32 == 0 || kb + 8 <= KLEN) {
                    ra[2 * kk]     = *(const f32x4*)(xrow + kb);
                    ra[2 * kk + 1] = *(const f32x4*)(xrow + kb + 4);
                } else {
                    ra[2 * kk] = f32x4{0.f,0.f,0.f,0.f};
                    ra[2 * kk + 1] = f32x4{0.f,0.f,0.f,0.f};
                }
            }
        }
        // write W tile
        #pragma unroll
        for (int j = 0; j < 6; ++j)
            *(ushort8*)((char*)sW + (j * 256 + t) * 16) = wr[j];
        __syncthreads();                       // tile ready
        // compute: NCH k-steps x 4 n-tiles
        #pragma unroll
        for (int kk = 0; kk < NCH; ++kk) {
            const int cch = kk * 4 + kg;
            const int c24 = cch & 24, c7 = cch & 7;
            const bf16x8 af = frag[kk];
            {
                const int n = r16;
                const bf16x8 bf = *(const bf16x8*)((const char*)sW + n * 384 + (c24 | (c7 ^ (n & 7))) * 16);
                acc0 = __builtin_amdgcn_mfma_f32_16x16x32_bf16(af, bf, acc0, 0, 0, 0);
            }
            {
                const int n = 16 + r16;
                const bf16x8 bf = *(const bf16x8*)((const char*)sW + n * 384 + (c24 | (c7 ^ (n & 7))) * 16);
                acc1 = __builtin_amdgcn_mfma_f32_16x16x32_bf16(af, bf, acc1, 0, 0, 0);
            }
            {
                const int n = 32 + r16;
                const bf16x8 bf = *(const bf16x8*)((const char*)sW + n * 384 + (c24 | (c7 ^ (n & 7))) * 16);
                acc2 = __builtin_amdgcn_mfma_f32_16x16x32_bf16(af, bf, acc2, 0, 0, 0);
            }
            {
                const int n = 48 + r16;
                const bf16x8 bf = *(const bf16x8*)((const char*)sW + n * 384 + (c24 | (c7 ^ (n & 7))) * 16);
                acc3 = __builtin_amdgcn_mfma_f32_16x16x32_bf16(af, bf, acc3, 0, 0, 0);
            }
        }
    }
    // C/D: col = lane&15 (=n offset), row = 4*(lane>>4)+reg (=sample offset)
    const float bz0 = bias[r16], bz1 = bias[16 + r16], bz2 = bias[32 + r16], bz3 = bias[48 + r16];
    const int rr = 4 * kg;
    #pragma unroll
    for (int reg = 0; reg < 4; ++reg) {
        const size_t base = (size_t)(s0 + w * 16 + rr + reg) * 128 + colbase;
        ivb[base +  0 + r16] = bfu(acc0[reg] + bz0);
        ivb[base + 16 + r16] = bfu(acc1[reg] + bz1);
        ivb[base + 32 + r16] = bfu(acc2[reg] + bz2);
        ivb[base + 48 + r16] = bfu(acc3[reg] + bz3);
    }
}

__global__ __launch_bounds__(256, 4)
void mica_enc(const float* __restrict__ f1, const float* __restrict__ f2,
              const unsigned short* __restrict__ W1p, const unsigned short* __restrict__ W2p,
              const float* __restrict__ be1, const float* __restrict__ be2,
              unsigned short* __restrict__ ivb) {
    __shared__ __align__(16) short sW[12288];   // 24 KB W tile
    const int t = threadIdx.x;
    const int s0 = blockIdx.x * SPB;
    encPk<6, 192, 768>(f1, W1p, be1, sW, ivb, 0,  s0, t);
    encPk<5, 160, 600>(f2, W2p, be2, sW, ivb, 64, s0, t);
}

// ---------------- tail (R7: back to R2-verified LDS form; no spills) ----------------
// 256 threads / 64 samples per block. sIV staged from ivb; s = t&63, q = t>>6.
__global__ __launch_bounds__(256, 2)
void mica_tail(const unsigned short* __restrict__ ivb,
               const float* __restrict__ Waffa, const float* __restrict__ Waffv,
               const float* __restrict__ Wa, const float* __restrict__ Wv,
               const float* __restrict__ Wca, const float* __restrict__ Wcv,
               const float* __restrict__ Wha, const float* __restrict__ Whv,
               const float* __restrict__ G, const float* __restrict__ cvec,
               float* __restrict__ out) {
    __shared__ float sIV[SPB * IVW];    // 33.8 KB
    __shared__ float red[4096];         // 16 KB reduction buffer
    const int t = threadIdx.x;
    const int s0 = blockIdx.x * SPB;

    // stage: thread handles row = t&63, 32 cols at cb = (t>>6)*32
    {
        const int row = t & 63, cb = (t >> 6) * 32;
        const unsigned short* src = ivb + (size_t)(s0 + row) * 128 + cb;
        #pragma unroll
        for (int j = 0; j < 4; ++j) {
            const ushort8 v = *(const ushort8*)(src + j * 8);
            f32x4 f0 = {b2f(v[0]), b2f(v[1]), b2f(v[2]), b2f(v[3])};
            f32x4 f1 = {b2f(v[4]), b2f(v[5]), b2f(v[6]), b2f(v[7])};
            *(f32x4*)(sIV + row * IVW + cb + j * 8)     = f0;
            *(f32x4*)(sIV + row * IVW + cb + j * 8 + 4) = f1;
        }
    }
    __syncthreads();

    const int s = t & 63;
    const int q = t >> 6;
    const float* iv = sIV + s * IVW;

    // step 3: moments (4-way split over k, 16 k each)
    float sii = 0.f, siv = 0.f, svv = 0.f;
    #pragma unroll
    for (int h = 0; h < 2; ++h) {
        const f32x4 a0 = *(const f32x4*)(iv + q * 16 + h * 8);
        const f32x4 a1 = *(const f32x4*)(iv + q * 16 + h * 8 + 4);
        const f32x4 b0 = *(const f32x4*)(iv + 64 + q * 16 + h * 8);
        const f32x4 b1 = *(const f32x4*)(iv + 64 + q * 16 + h * 8 + 4);
        #pragma unroll
        for (int j = 0; j < 4; ++j) {
            sii = fmaf(a0[j], a0[j], sii); siv = fmaf(a0[j], b0[j], siv); svv = fmaf(b0[j], b0[j], svv);
            sii = fmaf(a1[j], a1[j], sii); siv = fmaf(a1[j], b1[j], siv); svv = fmaf(b1[j], b1[j], svv);
        }
    }
    red[(q * 3 + 0) * 64 + s] = sii;
    red[(q * 3 + 1) * 64 + s] = siv;
    red[(q * 3 + 2) * 64 + s] = svv;
    __syncthreads();
    sii = 0.f; siv = 0.f; svv = 0.f;
    #pragma unroll
    for (int g = 0; g < 4; ++g) {
        sii += red[(g * 3 + 0) * 64 + s];
        siv += red[(g * 3 + 1) * 64 + s];
        svv += red[(g * 3 + 2) * 64 + s];
    }

    // step 4: gates (scale = 1/8)
    float ia[8], va[8];
    #pragma unroll
    for (int j = 0; j < 8; ++j) {
        ia[j] = tanhf((sii * Waffa[j * 2 + 0] + siv * Waffa[j * 2 + 1]) * 0.125f);
        va[j] = tanhf((siv * Waffv[j * 2 + 0] + svv * Waffv[j * 2 + 1]) * 0.125f);
    }

    // steps 5-6: H_a, H_v — this thread owns m = q*8 .. q*8+7
    float Ha[8], Hv[8];
    #pragma unroll
    for (int mi = 0; mi < 8; ++mi) {
        const int m = q * 8 + mi;
        float sa = 0.f, sv = 0.f;
        #pragma unroll
        for (int j = 0; j < 8; ++j) {
            sa = fmaf(ia[j], Wca[m * 8 + j], sa);
            sv = fmaf(va[j], Wcv[m * 8 + j], sv);
        }
        Ha[mi] = sa; Hv[mi] = sv;
    }
    for (int k4 = 0; k4 < 64; k4 += 4) {
        const f32x4 a4 = *(const f32x4*)(iv + k4);
        const f32x4 b4 = *(const f32x4*)(iv + 64 + k4);
        #pragma unroll
        for (int mi = 0; mi < 8; ++mi) {
            const int m = q * 8 + mi;
            const f32x4 wa = *(const f32x4*)(Wa + m * 64 + k4);
            const f32x4 wv = *(const f32x4*)(Wv + m * 64 + k4);
            #pragma unroll
            for (int j = 0; j < 4; ++j) {
                Ha[mi] = fmaf(a4[j], wa[j], Ha[mi]);
                Hv[mi] = fmaf(b4[j], wv[j], Hv[mi]);
            }
        }
    }
    #pragma unroll
    for (int mi = 0; mi < 8; ++mi) {
        Ha[mi] = fmaxf(ALPHA * Ha[mi], 0.f);
        Hv[mi] = fmaxf((1.f - ALPHA) * Hv[mi], 0.f);
    }

    __syncthreads();   // step-3 reads of red done before step-7 writes

    // step 7: ha/hv partials (8 m each), reduce via red
    #pragma unroll
    for (int j = 0; j < 8; ++j) {
        float hap = 0.f, hvp = 0.f;
        #pragma unroll
        for (int mi = 0; mi < 8; ++mi) {
            hap = fmaf(Ha[mi], Wha[j * 32 + q * 8 + mi], hap);
            hvp = fmaf(Hv[mi], Whv[j * 32 + q * 8 + mi], hvp);
        }
        red[(q * 16 + j) * 64 + s] = hap;
        red[(q * 16 + 8 + j) * 64 + s] = hvp;
    }
    __syncthreads();
    float ha[8], hv[8];
    #pragma unroll
    for (int j = 0; j < 8; ++j) {
        float sa = 0.f, sv = 0.f;
        #pragma unroll
        for (int g = 0; g < 4; ++g) {
            sa += red[(g * 16 + j) * 64 + s];
            sv += red[(g * 16 + 8 + j) * 64 + s];
        }
        ha[j] = sa; hv[j] = sv;
    }

    // step 9: out = X[144] * G + c — this thread: o = q*8 .. q*8+7
    float o8[8];
    #pragma unroll
    for (int oi = 0; oi < 8; ++oi) o8[oi] = cvec[q * 8 + oi];
    for (int k4 = 0; k4 < 128; k4 += 4) {
        const f32x4 a4 = *(const f32x4*)(iv + k4);
        #pragma unroll
        for (int kk = 0; kk < 4; ++kk) {
            const f32x4 g0 = *(const f32x4*)(G + (k4 + kk) * 32 + q * 8);
            const f32x4 g1 = *(const f32x4*)(G + (k4 + kk) * 32 + q * 8 + 4);
            #pragma unroll
            for (int oi = 0; oi < 4; ++oi) {
                o8[oi]     = fmaf(a4[kk], g0[oi], o8[oi]);
                o8[4 + oi] = fmaf(a4[kk], g1[oi], o8[4 + oi]);
            }
        }
    }
    #pragma unroll
    for (int j = 0; j < 8; ++j) {
        const float aj = ALPHA * ha[j];
        const float vj = (1.f - ALPHA) * hv[j];
        const f32x4 ga0 = *(const f32x4*)(G + (128 + j) * 32 + q * 8);
        const f32x4 ga1 = *(const f32x4*)(G + (128 + j) * 32 + q * 8 + 4);
        const f32x4 gv0 = *(const f32x4*)(G + (136 + j) * 32 + q * 8);
        const f32x4 gv1 = *(const f32x4*)(G + (136 + j) * 32 + q * 8 + 4);
        #pragma unroll
        for (int oi = 0; oi < 4; ++oi) {
            o8[oi]     = fmaf(aj, ga0[oi], o8[oi]);
            o8[4 + oi] = fmaf(aj, ga1[oi], o8[4 + oi]);
            o8[oi]     = fmaf(vj, gv0[oi], o8[oi]);
            o8[4 + oi] = fmaf(vj, gv1[oi], o8[4 + oi]);
        }
    }
    f32x4 v0 = {o8[0], o8[1], o8[2], o8[3]};
    f32x4 v1 = {o8[4], o8[5], o8[6], o8[7]};
    float* op = out + (size_t)(s0 + s) * 32 + q * 8;
    *(f32x4*)op = v0;
    *((f32x4*)op + 1) = v1;
}

extern "C" void kernel_launch(void* const* d_in, const int* in_sizes, int n_in,
                              void* d_out, int out_size, void* d_ws, size_t ws_size,
                              hipStream_t stream) {
    const float* f1    = (const float*)d_in[0];
    const float* f2    = (const float*)d_in[1];
    const float* We1   = (const float*)d_in[2];
    const float* be1   = (const float*)d_in[3];
    const float* We2   = (const float*)d_in[4];
    const float* be2   = (const float*)d_in[5];
    const float* Waffa = (const float*)d_in[6];
    const float* Waffv = (const float*)d_in[7];
    const float* Wa    = (const float*)d_in[8];
    const float* Wv    = (const float*)d_in[9];
    const float* Wca   = (const float*)d_in[10];
    const float* Wcv   = (const float*)d_in[11];
    const float* Wha   = (const float*)d_in[12];
    const float* Whv   = (const float*)d_in[13];
    const float* Wr1   = (const float*)d_in[14];
    const float* br1   = (const float*)d_in[15];
    const float* Wr2   = (const float*)d_in[16];
    const float* br2   = (const float*)d_in[17];
    float* outp = (float*)d_out;

    const int Btot = in_sizes[0] / 768;

    // ws layout: M[0,73728) G[73728,92160) c[92160,92288)
    //            W1p[92288,+98304) W2p[190592,+98304) ivb[288896, +B*256)
    float* M = (float*)d_ws;
    float* G = (float*)((char*)d_ws + 73728);
    float* c = (float*)((char*)d_ws + 92160);
    unsigned short* W1p = (unsigned short*)((char*)d_ws + 92288);
    unsigned short* W2p = (unsigned short*)((char*)d_ws + 190592);
    unsigned short* ivb = (unsigned short*)((char*)d_ws + 288896);

    prepA<<<(144 * 128 + 255) / 256, 256, 0, stream>>>(Wr1, M);
    prepB<<<(144 * 32 + 32 + 255) / 256, 256, 0, stream>>>(M, Wr2, br1, br2, G, c);
    prepWpk<<<48, 256, 0, stream>>>(We1, We2, W1p, W2p);
    mica_enc<<<Btot / SPB, 256, 0, stream>>>(f1, f2, W1p, W2p, be1, be2, ivb);
    mica_tail<<<Btot / SPB, 256, 0, stream>>>(ivb, Waffa, Waffv, Wa, Wv,
                                              Wca, Wcv, Wha, Whv, G, c, outp);
}